// Round 8
// baseline (234.223 us; speedup 1.0000x reference)
//
#include <hip/hip_runtime.h>
#include <hip/hip_fp16.h>
#include <cstdint>

#define T_DIM 64
#define IN_DIM 4100
#define OUT_DIM 12288
#define G_DIM 820
#define KCODE 256
#define GRP 5
#define KB32 205         /* k-blocks of 32 */
#define CHUNKS 41        /* 20 groups per chunk */
#define CH_G 20
#define KSPLIT 4
#define NBLK 192         /* 12288 / 64 */
#define LDS_STRIDE 168   /* halfs; 336 B/row = 21x16B, phase-20 bank walk */

typedef _Float16 f16x8 __attribute__((ext_vector_type(8)));
typedef float f32x4 __attribute__((ext_vector_type(4)));

__device__ float g_cbmax;                                // clamped cb_max
__device__ float g_xmax;                                 // clamped x_max*8
__device__ __align__(16) _Float16 g_cbq[2 * KCODE * 8];  // padded, pre-scaled fp16 cb
__device__ __align__(16) _Float16 g_xA[4 * KB32 * 64 * 8]; // A-frags, 16x16x32 lane order
__device__ __align__(16) float g_part[KSPLIT * T_DIM * OUT_DIM];

__device__ __forceinline__ float block_reduce_max(float m, float* sm) {
    for (int off = 32; off > 0; off >>= 1)
        m = fmaxf(m, __shfl_down(m, off));
    int tid = threadIdx.x;
    if ((tid & 63) == 0) sm[tid >> 6] = m;
    __syncthreads();
    float r = fmaxf(fmaxf(sm[0], sm[1]), fmaxf(sm[2], sm[3]));
    __syncthreads();
    return r;
}

// K2: blocks 0..204 each redundantly scan x (L2-resident, deterministic identical
// max) then quantize their slice into 16x16x32 A-fragment order. Block 205 does
// codebook canonicalize + scale. (k1 merged away.)
__global__ void __launch_bounds__(256) k2_quant(const float* __restrict__ x,
                                                const void* __restrict__ cbraw) {
    __shared__ float sm[4];
    int tid = threadIdx.x, bid = blockIdx.x;

    if (bid == 205) {
        // dtype probe (verified R2): fp16 codebooks may arrive upcast to f32.
        unsigned u0 = *(const unsigned*)cbraw;
        bool is_f32 = (((u0 >> 23) & 0xFF) >= 100);
        float mm = 0.f;
        for (int i = tid; i < 2 * KCODE * GRP; i += 256) {
            float v = is_f32 ? ((const float*)cbraw)[i]
                             : (float)((const _Float16*)cbraw)[i];
            mm = fmaxf(mm, fabsf(v));
        }
        float cbm = fmaxf(block_reduce_max(mm, sm), 1.0f);
        if (tid == 0) g_cbmax = cbm;
        for (int e = tid; e < 2 * KCODE; e += 256) {
            f16x8 v = {};
            #pragma unroll
            for (int j = 0; j < GRP; ++j) {
                float w = is_f32 ? ((const float*)cbraw)[e * GRP + j]
                                 : (float)((const _Float16*)cbraw)[e * GRP + j];
                v[j] = (_Float16)(w / cbm);
            }
            *(f16x8*)&g_cbq[e * 8] = v;
        }
        return;
    }

    // full |x| max: 65600 float4 reads, L2-served after first touch
    float m = 0.f;
    const f32x4* x4 = (const f32x4*)x;
    for (int i = tid; i < T_DIM * IN_DIM / 4; i += 256) {
        f32x4 v = x4[i];
        m = fmaxf(m, fmaxf(fmaxf(fabsf(v[0]), fabsf(v[1])),
                           fmaxf(fabsf(v[2]), fabsf(v[3]))));
    }
    float xm = fmaxf(block_reduce_max(m, sm), 1.0f) * 8.0f;
    if (bid == 0 && tid == 0) g_xmax = xm;

    // quantize: g_xA[((t16*KB32+kb32)*64+lane)*8+j] = fp16(x[t16*16+(lane&15)]
    //                                                  [(kb32*4+(lane>>4))*5+j]/xm)
    int gt = bid * 256 + tid;               // [0, 205*256) == 4*KB32*64
    int lane = gt & 63;
    int rest = gt >> 6;
    int kb32 = rest % KB32;
    int t16 = rest / KB32;
    int t = t16 * 16 + (lane & 15);
    int g = kb32 * 4 + (lane >> 4);
    const float* xp = x + (size_t)t * IN_DIM + g * GRP;
    float inv = 1.0f / xm;
    f16x8 v = {};
    #pragma unroll
    for (int j = 0; j < GRP; ++j) v[j] = (_Float16)(xp[j] * inv);
    *(f16x8*)&g_xA[(size_t)gt * 8] = v;
}

// K3: GEMM. 768 blocks (192 o-tiles x KSPLIT=4), 4 waves. Tile 64(T)x64(O).
// Wave = o-quadrant: B-frag read once per k-step, reused across 4 t-tiles
// (4x fewer B ds_reads). A-frags from global (L2), issued before the barrier.
__global__ void __launch_bounds__(256, 3) k3_gemm(const int* __restrict__ indices) {
    __shared__ alignas(16) _Float16 w_lds[64 * LDS_STRIDE];
    __shared__ f16x8 cb_sh[2 * KCODE];

    int tid = threadIdx.x;
    int nb = blockIdx.x % NBLK;
    int ksp = blockIdx.x / NBLK;
    int n_base = nb * 64;

    for (int e = tid; e < 2 * KCODE; e += 256)
        cb_sh[e] = *(const f16x8*)&g_cbq[e * 8];

    // per-thread staging slots: 64 o-rows x 20 groups = 5*256
    int sro[5], sgl[5];
    #pragma unroll
    for (int j = 0; j < 5; ++j) {
        int s = tid + j * 256;
        sro[j] = s / 20; sgl[j] = s - sro[j] * 20;
    }

    const int c0 = (CHUNKS * ksp) / KSPLIT;
    const int c1 = (CHUNKS * (ksp + 1)) / KSPLIT;
    const int wid = tid >> 6, lane = tid & 63;
    const int q = lane >> 4, r16 = lane & 15;

    f32x4 acc[4] = {};
    int2 idxr[5];
    auto pref_idx = [&](int c) {
        int g0 = c * CH_G;
        #pragma unroll
        for (int j = 0; j < 5; ++j)
            idxr[j] = *(const int2*)&indices[(size_t)(n_base + sro[j]) * (G_DIM * 2)
                                             + (size_t)(g0 + sgl[j]) * 2];
    };

    pref_idx(c0);
    __syncthreads();   // cb_sh ready

    for (int c = c0; c < c1; ++c) {
        // stage W tile from prefetched indices (gather + fp16 add, matches ref)
        #pragma unroll
        for (int j = 0; j < 5; ++j) {
            f16x8 w = cb_sh[idxr[j].x] + cb_sh[KCODE + idxr[j].y];
            *(f16x8*)&w_lds[sro[j] * LDS_STRIDE + sgl[j] * 8] = w;
        }
        // A-frags for this chunk: global/L2, independent of w_lds -> issue
        // before the barrier so they complete under it. [t16][kk] order.
        uint4 ar20[20];
        #pragma unroll
        for (int t16 = 0; t16 < 4; ++t16)
            #pragma unroll
            for (int kk = 0; kk < 5; ++kk)
                ar20[t16 * 5 + kk] = *(const uint4*)
                    &g_xA[(size_t)((t16 * KB32 + c * 5 + kk) * 64 + lane) * 8];
        __syncthreads();            // W tile ready
        if (c + 1 < c1) pref_idx(c + 1);   // next indices fly under MFMA phase
        #pragma unroll
        for (int kk = 0; kk < 5; ++kk) {
            f16x8 b = *(const f16x8*)&w_lds[(wid * 16 + r16) * LDS_STRIDE + kk * 32 + q * 8];
            #pragma unroll
            for (int t16 = 0; t16 < 4; ++t16)
                acc[t16] = __builtin_amdgcn_mfma_f32_16x16x32_f16(
                    *(f16x8*)&ar20[t16 * 5 + kk], b, acc[t16], 0, 0, 0);
        }
        __syncthreads();            // W tile consumed
    }

    // C/D: col = lane&15 -> o within wave's 16-o slab, row = q*4+reg -> t
    float* pp = g_part + (size_t)ksp * (T_DIM * OUT_DIM);
    int o = n_base + wid * 16 + r16;
    #pragma unroll
    for (int t16 = 0; t16 < 4; ++t16) {
        #pragma unroll
        for (int rr = 0; rr < 4; ++rr) {
            int t = t16 * 16 + q * 4 + rr;
            pp[t * OUT_DIM + o] = acc[t16][rr];
        }
    }
}

// K4: sum K-split partials, scale by xm*cbm*scales[o], nan_to_num, store float4.
__global__ void __launch_bounds__(256) k4_final(const float* __restrict__ scales,
                                                float* __restrict__ out) {
    int i4 = blockIdx.x * 256 + threadIdx.x;
    if (i4 >= T_DIM * OUT_DIM / 4) return;
    float s = g_xmax * g_cbmax;
    const f32x4* p = (const f32x4*)g_part;
    const int Q = T_DIM * OUT_DIM / 4;
    f32x4 v = p[i4];
    #pragma unroll
    for (int k = 1; k < KSPLIT; ++k) v += p[k * Q + i4];
    int o4 = i4 % (OUT_DIM / 4);
    f32x4 sc = *(const f32x4*)&scales[o4 * 4];
    f32x4 r;
    #pragma unroll
    for (int j = 0; j < 4; ++j) {
        float u = v[j] * s * sc[j];
        if (!isfinite(u)) u = 0.f;
        r[j] = u;
    }
    ((f32x4*)out)[i4] = r;
}

extern "C" void kernel_launch(void* const* d_in, const int* in_sizes, int n_in,
                              void* d_out, int out_size, void* d_ws, size_t ws_size,
                              hipStream_t stream) {
    const float* x = (const float*)d_in[0];
    const int* indices = (const int*)d_in[1];
    const void* cbraw = (const void*)d_in[2];
    const float* scales = (const float*)d_in[3];
    float* out = (float*)d_out;
    (void)d_ws; (void)ws_size; (void)n_in; (void)in_sizes; (void)out_size;

    k2_quant<<<206, 256, 0, stream>>>(x, cbraw);
    k3_gemm<<<NBLK * KSPLIT, 256, 0, stream>>>(indices);
    k4_final<<<T_DIM * OUT_DIM / 4 / 256, 256, 0, stream>>>(scales, out);
}

// Round 9
// 156.915 us; speedup vs baseline: 1.4927x; 1.4927x over previous
//
#include <hip/hip_runtime.h>
#include <hip/hip_fp16.h>
#include <cstdint>

#define T_DIM 64
#define IN_DIM 4100
#define OUT_DIM 12288
#define G_DIM 820
#define KCODE 256
#define GRP 5
#define KB32 205         /* k-blocks of 32 */
#define CHUNKS 41        /* 20 groups per chunk */
#define CH_G 20
#define KSPLIT 4
#define NBLK 192         /* 12288 / 64 */
#define LDS_STRIDE 168   /* halfs; 336 B/row */

typedef _Float16 f16x8 __attribute__((ext_vector_type(8)));
typedef float f32x4 __attribute__((ext_vector_type(4)));

__device__ float g_pmax[256];                            // per-block |x| partial max
__device__ float g_cbmax;                                // clamped cb_max
__device__ float g_xmax;                                 // clamped x_max*8
__device__ __align__(16) _Float16 g_cbq[2 * KCODE * 8];  // padded, pre-scaled fp16 cb
__device__ __align__(16) _Float16 g_xA[4 * KB32 * 64 * 8]; // A-frags, 16x16x32 lane order
__device__ __align__(16) float g_part[KSPLIT * T_DIM * OUT_DIM];

__device__ __forceinline__ float block_reduce_max(float m, float* sm) {
    for (int off = 32; off > 0; off >>= 1)
        m = fmaxf(m, __shfl_down(m, off));
    int tid = threadIdx.x;
    if ((tid & 63) == 0) sm[tid >> 6] = m;
    __syncthreads();
    float r = fmaxf(fmaxf(sm[0], sm[1]), fmaxf(sm[2], sm[3]));
    __syncthreads();
    return r;
}

// K1: per-block |x| partial max (256 blocks, 1 float4/thread); block 0 also
// canonicalizes + pre-scales the codebooks. [R4-proven]
__global__ void __launch_bounds__(256) k1_absmax_cb(const float* __restrict__ x,
                                                    const void* __restrict__ cbraw) {
    __shared__ float sm[4];
    int tid = threadIdx.x, bid = blockIdx.x;
    float m = 0.f;
    for (int i = bid * 256 + tid; i < T_DIM * IN_DIM; i += 256 * 256)
        m = fmaxf(m, fabsf(x[i]));
    float r = block_reduce_max(m, sm);
    if (tid == 0) g_pmax[bid] = r;

    if (bid == 0) {
        // dtype probe (verified R2): fp16 codebooks may arrive upcast to f32.
        unsigned u0 = *(const unsigned*)cbraw;
        bool is_f32 = (((u0 >> 23) & 0xFF) >= 100);
        float mm = 0.f;
        for (int i = tid; i < 2 * KCODE * GRP; i += 256) {
            float v = is_f32 ? ((const float*)cbraw)[i]
                             : (float)((const _Float16*)cbraw)[i];
            mm = fmaxf(mm, fabsf(v));
        }
        float cbm = fmaxf(block_reduce_max(mm, sm), 1.0f);
        if (tid == 0) g_cbmax = cbm;
        for (int e = tid; e < 2 * KCODE; e += 256) {
            f16x8 v = {};
            #pragma unroll
            for (int j = 0; j < GRP; ++j) {
                float w = is_f32 ? ((const float*)cbraw)[e * GRP + j]
                                 : (float)((const _Float16*)cbraw)[e * GRP + j];
                v[j] = (_Float16)(w / cbm);
            }
            *(f16x8*)&g_cbq[e * 8] = v;
        }
    }
}

// K2: reduce partials -> xm; quantize x straight into 16x16x32 A-fragment order.
// g_xA[((t16*KB32+kb32)*64+lane)*8+j] = fp16(x[t16*16+(lane&15)]
//                                             [(kb32*4+(lane>>4))*5+j] / xm), j<5
__global__ void __launch_bounds__(256) k2_quant(const float* __restrict__ x) {
    __shared__ float sm[4];
    int tid = threadIdx.x;
    float xm = fmaxf(block_reduce_max(g_pmax[tid], sm), 1.0f) * 8.0f;
    if (blockIdx.x == 0 && tid == 0) g_xmax = xm;

    int gt = blockIdx.x * 256 + tid;        // [0, 205*256) == 4*KB32*64
    int lane = gt & 63;
    int rest = gt >> 6;
    int kb32 = rest % KB32;
    int t16 = rest / KB32;
    int t = t16 * 16 + (lane & 15);
    int g = kb32 * 4 + (lane >> 4);
    const float* xp = x + (size_t)t * IN_DIM + g * GRP;
    float inv = 1.0f / xm;
    f16x8 v = {};
    #pragma unroll
    for (int j = 0; j < GRP; ++j) v[j] = (_Float16)(xp[j] * inv);
    *(f16x8*)&g_xA[(size_t)gt * 8] = v;
}

// K3: GEMM. 768 blocks (192 o-tiles x KSPLIT=4), 4 waves. Tile 64(T)x64(O).
// Wave = o-quadrant: B-frag read once per k-step, reused across 4 t-tiles
// (4x fewer B ds_reads vs R4). A-frags from global (L2), issued pre-barrier.
__global__ void __launch_bounds__(256, 3) k3_gemm(const int* __restrict__ indices) {
    __shared__ alignas(16) _Float16 w_lds[64 * LDS_STRIDE];
    __shared__ f16x8 cb_sh[2 * KCODE];

    int tid = threadIdx.x;
    int nb = blockIdx.x % NBLK;
    int ksp = blockIdx.x / NBLK;
    int n_base = nb * 64;

    for (int e = tid; e < 2 * KCODE; e += 256)
        cb_sh[e] = *(const f16x8*)&g_cbq[e * 8];

    // per-thread staging slots: 64 o-rows x 20 groups = 5*256
    int sro[5], sgl[5];
    #pragma unroll
    for (int j = 0; j < 5; ++j) {
        int s = tid + j * 256;
        sro[j] = s / 20; sgl[j] = s - sro[j] * 20;
    }

    const int c0 = (CHUNKS * ksp) / KSPLIT;
    const int c1 = (CHUNKS * (ksp + 1)) / KSPLIT;
    const int wid = tid >> 6, lane = tid & 63;
    const int q = lane >> 4, r16 = lane & 15;

    f32x4 acc[4] = {};
    int2 idxr[5];
    auto pref_idx = [&](int c) {
        int g0 = c * CH_G;
        #pragma unroll
        for (int j = 0; j < 5; ++j)
            idxr[j] = *(const int2*)&indices[(size_t)(n_base + sro[j]) * (G_DIM * 2)
                                             + (size_t)(g0 + sgl[j]) * 2];
    };

    pref_idx(c0);
    __syncthreads();   // cb_sh ready

    for (int c = c0; c < c1; ++c) {
        // stage W tile from prefetched indices (gather + fp16 add, matches ref)
        #pragma unroll
        for (int j = 0; j < 5; ++j) {
            f16x8 w = cb_sh[idxr[j].x] + cb_sh[KCODE + idxr[j].y];
            *(f16x8*)&w_lds[sro[j] * LDS_STRIDE + sgl[j] * 8] = w;
        }
        // A-frags for this chunk: global/L2, independent of w_lds -> issue
        // before the barrier so they complete under it. [t16][kk] order.
        uint4 ar20[20];
        #pragma unroll
        for (int t16 = 0; t16 < 4; ++t16)
            #pragma unroll
            for (int kk = 0; kk < 5; ++kk)
                ar20[t16 * 5 + kk] = *(const uint4*)
                    &g_xA[(size_t)((t16 * KB32 + c * 5 + kk) * 64 + lane) * 8];
        __syncthreads();            // W tile ready
        if (c + 1 < c1) pref_idx(c + 1);   // next indices fly under MFMA phase
        #pragma unroll
        for (int kk = 0; kk < 5; ++kk) {
            f16x8 b = *(const f16x8*)&w_lds[(wid * 16 + r16) * LDS_STRIDE + kk * 32 + q * 8];
            #pragma unroll
            for (int t16 = 0; t16 < 4; ++t16)
                acc[t16] = __builtin_amdgcn_mfma_f32_16x16x32_f16(
                    *(f16x8*)&ar20[t16 * 5 + kk], b, acc[t16], 0, 0, 0);
        }
        __syncthreads();            // W tile consumed
    }

    // C/D: col = lane&15 -> o within wave's 16-o slab, row = q*4+reg -> t
    float* pp = g_part + (size_t)ksp * (T_DIM * OUT_DIM);
    int o = n_base + wid * 16 + r16;
    #pragma unroll
    for (int t16 = 0; t16 < 4; ++t16) {
        #pragma unroll
        for (int rr = 0; rr < 4; ++rr) {
            int t = t16 * 16 + q * 4 + rr;
            pp[t * OUT_DIM + o] = acc[t16][rr];
        }
    }
}

// K4: sum K-split partials, scale by xm*cbm*scales[o], nan_to_num, store float4.
__global__ void __launch_bounds__(256) k4_final(const float* __restrict__ scales,
                                                float* __restrict__ out) {
    int i4 = blockIdx.x * 256 + threadIdx.x;
    if (i4 >= T_DIM * OUT_DIM / 4) return;
    float s = g_xmax * g_cbmax;
    const f32x4* p = (const f32x4*)g_part;
    const int Q = T_DIM * OUT_DIM / 4;
    f32x4 v = p[i4];
    #pragma unroll
    for (int k = 1; k < KSPLIT; ++k) v += p[k * Q + i4];
    int o4 = i4 % (OUT_DIM / 4);
    f32x4 sc = *(const f32x4*)&scales[o4 * 4];
    f32x4 r;
    #pragma unroll
    for (int j = 0; j < 4; ++j) {
        float u = v[j] * s * sc[j];
        if (!isfinite(u)) u = 0.f;
        r[j] = u;
    }
    ((f32x4*)out)[i4] = r;
}

extern "C" void kernel_launch(void* const* d_in, const int* in_sizes, int n_in,
                              void* d_out, int out_size, void* d_ws, size_t ws_size,
                              hipStream_t stream) {
    const float* x = (const float*)d_in[0];
    const int* indices = (const int*)d_in[1];
    const void* cbraw = (const void*)d_in[2];
    const float* scales = (const float*)d_in[3];
    float* out = (float*)d_out;
    (void)d_ws; (void)ws_size; (void)n_in; (void)in_sizes; (void)out_size;

    k1_absmax_cb<<<256, 256, 0, stream>>>(x, cbraw);
    k2_quant<<<205, 256, 0, stream>>>(x);
    k3_gemm<<<NBLK * KSPLIT, 256, 0, stream>>>(indices);
    k4_final<<<T_DIM * OUT_DIM / 4 / 256, 256, 0, stream>>>(scales, out);
}